// Round 8
// baseline (278.874 us; speedup 1.0000x reference)
//
#include <hip/hip_runtime.h>
#include <math.h>
#include <stdint.h>

#define B_ROWS 2048
#define D_DIM  512
#define V_COLS 32000
#define BM 128                          // block rows
#define BN 64                           // block cols (B K-resident)
#define KSTEPS 16                       // 512 / 32
#define NCT    (V_COLS / BN)            // 500 col tiles
#define S_SC   30.0f
#define COS_M  0.8775825618903728f      // cos(0.5)
#define SIN_M  0.479425538604203f       // sin(0.5)

typedef float f32x4 __attribute__((ext_vector_type(4)));
typedef long  i64a  __attribute__((aligned(8)));

__device__ __forceinline__ void load16_to_lds(const void* g, void* l) {
  __builtin_amdgcn_global_load_lds(
      (__attribute__((address_space(1))) void*)(g),
      (__attribute__((address_space(3))) void*)(l),
      16, 0, 0);
}

// ---------- kernel 1: fused row L2-normalize (x,W) fp32 -> fp8 e4m3, + zero rowsum/out ----------
__global__ void fused_norm_kernel(const float* __restrict__ x,
                                  const float* __restrict__ W,
                                  uint8_t* __restrict__ nx,
                                  uint8_t* __restrict__ nw,
                                  float* __restrict__ rowsum,
                                  float* __restrict__ out) {
  if (blockIdx.x == 0 && threadIdx.x == 0) out[0] = 0.f;
  if (blockIdx.x < B_ROWS / 256) rowsum[blockIdx.x * 256 + threadIdx.x] = 0.f;
  const int lane = threadIdx.x & 63;
  const int wave = threadIdx.x >> 6;
  const int gr   = blockIdx.x * 4 + wave;
  const float* src;
  uint8_t* dst;
  if (gr < B_ROWS) {
    src = x + (size_t)gr * D_DIM;
    dst = nx + (size_t)gr * D_DIM;
  } else {
    src = W + (size_t)(gr - B_ROWS) * D_DIM;
    dst = nw + (size_t)(gr - B_ROWS) * D_DIM;
  }
  const float4* r4 = (const float4*)src;
  float4 v0 = r4[2 * lane];
  float4 v1 = r4[2 * lane + 1];
  float ss = v0.x*v0.x + v0.y*v0.y + v0.z*v0.z + v0.w*v0.w
           + v1.x*v1.x + v1.y*v1.y + v1.z*v1.z + v1.w*v1.w;
  #pragma unroll
  for (int off = 32; off >= 1; off >>= 1) ss += __shfl_xor(ss, off, 64);
  float inv = 1.0f / fmaxf(sqrtf(ss), 1e-12f);
  int p0 = __builtin_amdgcn_cvt_pk_fp8_f32(v0.x * inv, v0.y * inv, 0, false);
  p0     = __builtin_amdgcn_cvt_pk_fp8_f32(v0.z * inv, v0.w * inv, p0, true);
  int p1 = __builtin_amdgcn_cvt_pk_fp8_f32(v1.x * inv, v1.y * inv, 0, false);
  p1     = __builtin_amdgcn_cvt_pk_fp8_f32(v1.z * inv, v1.w * inv, p1, true);
  ((int2*)dst)[lane] = make_int2(p0, p1);
}

// ---------- kernel 2: fp8 GEMM with K-RESIDENT B tile ----------
// Block = 256 thr / 4 waves, C-tile 128x64, 4 row-tiles per block (K=512-resident B).
// Grid 2048: c = id&511 (64-col tile; same-c blocks differ by 512 => same XCD under
// id%8 dispatch -> per-XCD working set = nw slice ~2 MB + nx 1 MB < 4 MB L2).
// B: 64 cols x 512 B fp8 = 32 KB LDS, staged ONCE (8 global_load_lds/wave + 1 barrier).
// A: wave-private 32 rows x 32 B = 1 KB per K-step, double-buffered (8 KB total);
//    1 load/step issued 1 step ahead, vmcnt(1) -> only VMEM dep in the whole K-loop.
// Swizzles: A = R6-proven; B: 16B chunk j of col c stored at slot j^(c&15) -> frag
// ds_read_b64 lands 2-way bank aliasing max (free, m136).
__global__ __launch_bounds__(256, 4)
void arc_gemm_kernel(const uint8_t* __restrict__ nx,
                     const uint8_t* __restrict__ nw,
                     const int* __restrict__ labels,
                     float* __restrict__ rowsum,
                     float* __restrict__ lbl_logit) {
  __shared__ uint8_t sB[BN * 512];        // 32 KB, col c at c*512, 16B-chunk swizzled
  __shared__ uint8_t sA[2][4][1024];      // 8 KB, [buf][wave][32 rows x 32 B]

  const int id = blockIdx.x;
  const int c9 = id & 511;
  if (c9 >= NCT) return;
  const int rg = id >> 9;                 // 0..3 -> row tiles rg*4 .. rg*4+3
  const int n0 = c9 * BN;
  const int mBase = rg * 4 * BM;

  const int tid  = threadIdx.x;
  const int wave = tid >> 6;
  const int lane = tid & 63;
  const int quad = lane >> 4;
  const int l16  = lane & 15;

  // ---- stage B (once): inst t covers block-local cols {c0, c0+1}; lane's col is
  // c0 + (lane>>5), 16B slot (lane&31), fetching global chunk slot^(col&15).
  #pragma unroll
  for (int t = 0; t < 8; ++t) {
    const int c0 = wave * 16 + t * 2;            // wave-uniform LDS col base
    const int cl = c0 + (lane >> 5);
    const int sl = lane & 31;
    const int jg = sl ^ (cl & 15);
    load16_to_lds(nw + (size_t)(n0 + cl) * 512 + jg * 16, &sB[c0 * 512]);
  }

  // ---- A staging (R6-proven swizzle): lane covers row lane>>1, 16B half
  const int hoff = (((lane & 1) ^ ((lane >> 3) & 1)) << 4);
  const uint8_t* gA = nx + (size_t)(mBase + wave * 32 + (lane >> 1)) * 512 + hoff;
  load16_to_lds(gA, &sA[0][wave][0]);            // (i=0, ks=0) -> buf 0

  // ---- label preload (loads hidden behind the prologue wait)
  int lbl4[4];
  #pragma unroll
  for (int i = 0; i < 4; ++i)
    lbl4[i] = labels[mBase + i * BM + wave * 32 + (lane & 31)];

  asm volatile("s_waitcnt vmcnt(0)" ::: "memory");
  __syncthreads();                               // B + first A resident (ONLY barrier)

  // frag-read offsets
  const int sw   = ((l16 >> 2) & 1) << 1;
  const int aOff = l16 * 32 + ((quad ^ sw) << 3);          // + mi*512
  const int bOff = l16 * 512 + ((quad & 1) << 3);          // + ni*8192 + slot*16

  f32x4 acc[2][4];
  #pragma unroll
  for (int mi = 0; mi < 2; ++mi)
    #pragma unroll
    for (int ni = 0; ni < 4; ++ni) acc[mi][ni] = (f32x4){0.f, 0.f, 0.f, 0.f};

  for (int i = 0; i < 4; ++i) {
    #pragma unroll
    for (int ks = 0; ks < KSTEPS; ++ks) {
      // WAR: prior ds_reads of the A-buffer about to be overwritten are done
      asm volatile("s_waitcnt lgkmcnt(0)" ::: "memory");
      if (ks < KSTEPS - 1 || i < 3) {            // stage next A slice (1 KB)
        const int i2  = (ks < KSTEPS - 1) ? i : i + 1;
        const int ks2 = (ks + 1) & 15;
        load16_to_lds(gA + (size_t)(i2 * BM) * 512 + ks2 * 32, &sA[(ks + 1) & 1][wave][0]);
        asm volatile("s_waitcnt vmcnt(1)" ::: "memory");   // slice ks resident; next in flight
      } else {
        asm volatile("s_waitcnt vmcnt(0)" ::: "memory");   // final slice resident
      }

      const uint8_t* bA = &sA[ks & 1][wave][0];
      i64a a_[2], b_[4];
      a_[0] = *(const i64a*)(bA + aOff);
      a_[1] = *(const i64a*)(bA + 512 + aOff);
      const int slot = ((((ks << 1) | (quad >> 1)) ^ l16) << 4);
      #pragma unroll
      for (int ni = 0; ni < 4; ++ni)
        b_[ni] = *(const i64a*)(&sB[ni * 8192] + bOff + slot);
      #pragma unroll
      for (int mi = 0; mi < 2; ++mi)
        #pragma unroll
        for (int ni = 0; ni < 4; ++ni)
          acc[mi][ni] = __builtin_amdgcn_mfma_f32_16x16x32_fp8_fp8(a_[mi], b_[ni], acc[mi][ni], 0, 0, 0);
    }

    // ---- epilogue for row tile rg*4+i. C/D: col = l16, row = quad*4 + reg (+mi*16).
    const int rm0 = mBase + i * BM + wave * 32;
    #pragma unroll
    for (int mi = 0; mi < 2; ++mi) {
      #pragma unroll
      for (int r = 0; r < 4; ++r) {
        const int rw   = mi * 16 + quad * 4 + r;         // 0..31
        const int grow = rm0 + rw;
        const int lbl  = __shfl(lbl4[i], rw, 64);
        float rsum = 0.f;
        #pragma unroll
        for (int ni = 0; ni < 4; ++ni) {
          float c = acc[mi][ni][r];
          const int gcol = n0 + ni * 16 + l16;
          if (gcol == lbl) {
            float sy  = sqrtf(fminf(1.f, fmaxf(0.f, 1.f - c * c)));
            float phi = c * COS_M - sy * SIN_M;
            lbl_logit[grow] = S_SC * phi;                // exactly one lane grid-wide
            c = phi;
          }
          rsum += __expf(S_SC * c - 30.0f);              // fixed shift: logits in [-30,30]
        }
        #pragma unroll
        for (int off = 1; off < 16; off <<= 1)
          rsum += __shfl_xor(rsum, off, 64);
        if (l16 == 0) atomicAdd(&rowsum[grow], rsum);
      }
    }
    #pragma unroll
    for (int mi = 0; mi < 2; ++mi)
      #pragma unroll
      for (int ni = 0; ni < 4; ++ni) acc[mi][ni] = (f32x4){0.f, 0.f, 0.f, 0.f};
  }
}

// ---------- kernel 3: per-row loss + global mean ----------
__global__ void arc_finish_kernel(const float* __restrict__ rowsum,
                                  const float* __restrict__ lbl_logit,
                                  float* __restrict__ out) {
  const int row  = blockIdx.x * 256 + threadIdx.x;   // 8 blocks x 256
  const int lane = threadIdx.x & 63;
  const int wave = threadIdx.x >> 6;
  float v = (30.0f + logf(rowsum[row]) - lbl_logit[row]) * (1.0f / (float)B_ROWS);
  #pragma unroll
  for (int off = 32; off >= 1; off >>= 1) v += __shfl_xor(v, off, 64);
  __shared__ float wsum[4];
  if (lane == 0) wsum[wave] = v;
  __syncthreads();
  if (threadIdx.x == 0) atomicAdd(out, wsum[0] + wsum[1] + wsum[2] + wsum[3]);
}

// ---------- launch ----------
extern "C" void kernel_launch(void* const* d_in, const int* in_sizes, int n_in,
                              void* d_out, int out_size, void* d_ws, size_t ws_size,
                              hipStream_t stream) {
  const float* x      = (const float*)d_in[0];
  const float* W      = (const float*)d_in[1];
  const int*   labels = (const int*)d_in[2];
  float* out = (float*)d_out;

  char* ws = (char*)d_ws;
  uint8_t* nx = (uint8_t*)ws;                                       // 1 MB
  uint8_t* nw = (uint8_t*)(ws + (size_t)B_ROWS * D_DIM);            // 16.4 MB
  char* p = ws + (size_t)B_ROWS * D_DIM + (size_t)V_COLS * D_DIM;
  float* rowsum    = (float*)p;  p += (size_t)B_ROWS * 4;           // 8 KB
  float* lbl_logit = (float*)p;                                     // 8 KB

  hipLaunchKernelGGL(fused_norm_kernel, dim3((B_ROWS + V_COLS) / 4), dim3(256), 0, stream,
                     x, W, nx, nw, rowsum, out);
  hipLaunchKernelGGL(arc_gemm_kernel, dim3(512 * 4), dim3(256), 0, stream,
                     nx, nw, labels, rowsum, lbl_logit);
  hipLaunchKernelGGL(arc_finish_kernel, dim3(B_ROWS / 256), dim3(256), 0, stream,
                     rowsum, lbl_logit, out);
}